// Round 11
// baseline (180.357 us; speedup 1.0000x reference)
//
#include <hip/hip_runtime.h>
#include <hip/hip_bf16.h>

#define T_TOK 2048
#define H_DIM 768
#define E_NUM 16
#define F_DIM 768
#define TWOF 1536
#define TOPK 4
#define NASSIGN 8192
#define BM 256
#define BK 64
#define BN 64
#define KT 12            /* 768/64 k-tiles */
#define NTILE 48         /* padded slots / BM = 12288/256 */
#define NSLOTP (NTILE * BM)
#define MAXT1 5          /* max tiles per expert (count <= 1280) */
#define CHUNK (BM * BK)  /* 16384 halfwords per A/act chunk */
#define WTILE (BN * BK)  /* 4096 halfwords per weight tile */

typedef __bf16 bf16x8 __attribute__((ext_vector_type(8)));
typedef unsigned short us8 __attribute__((ext_vector_type(8)));
typedef unsigned uint4v __attribute__((ext_vector_type(4)));
typedef float f32x4 __attribute__((ext_vector_type(4)));

__device__ __forceinline__ unsigned short f2bf(float f) {
  unsigned u = __float_as_uint(f);
  u += 0x7FFF + ((u >> 16) & 1);
  return (unsigned short)(u >> 16);
}

// packed f32x2 -> bf16x2 (RNE), 1 VALU instr; lo halfword = first arg
__device__ __forceinline__ unsigned cvt_pk(float lo, float hi) {
  unsigned r;
  asm("v_cvt_pk_bf16_f32 %0, %1, %2" : "=v"(r) : "v"(lo), "v"(hi));
  return r;
}

__device__ __forceinline__ void gl_lds16(const unsigned short* g, unsigned short* l) {
  __builtin_amdgcn_global_load_lds(
      (const __attribute__((address_space(1))) unsigned int*)g,
      (__attribute__((address_space(3))) unsigned int*)l, 16, 0, 0);
}

// ---------------- 1. router: LDS-staged fp64-acc logits, top-4, softmax ----------------
__global__ __launch_bounds__(256)
void router_kernel(const float* __restrict__ x, const float* __restrict__ rw,
                   const float* __restrict__ rb, float* __restrict__ scores,
                   int* __restrict__ tk_idx, float* __restrict__ tk_w,
                   int* __restrict__ tmap, float* __restrict__ wgrp) {
  __shared__ float xs[16][772];   // stride 772: 16B aligned, 2-way banks max
  __shared__ float ws[16][772];
  __shared__ float lg[16][16];
  __shared__ float sc[16][16];
  const int tid = threadIdx.x;
  const int t0 = blockIdx.x * 16;
  if (tid < 96) {                 // 128 blocks x 96 = NSLOTP init
    tmap[blockIdx.x * 96 + tid] = 0;
    wgrp[blockIdx.x * 96 + tid] = 0.0f;
  }
  for (int v = tid; v < 16 * 192; v += 256) {
    const int r = v / 192, c = (v % 192) * 4;
    *(f32x4*)&xs[r][c] = *(const f32x4*)&x[(size_t)(t0 + r) * H_DIM + c];
    *(f32x4*)&ws[r][c] = *(const f32x4*)&rw[(size_t)r * H_DIM + c];
  }
  __syncthreads();
  const int t = tid & 15, e = tid >> 4;
  double a0 = 0, a1 = 0, a2 = 0, a3 = 0;
  #pragma unroll 4
  for (int h = 0; h < 768; h += 4) {
    const f32x4 xv = *(const f32x4*)&xs[t][h];
    const f32x4 wv = *(const f32x4*)&ws[e][h];
    a0 += (double)xv[0] * (double)wv[0];
    a1 += (double)xv[1] * (double)wv[1];
    a2 += (double)xv[2] * (double)wv[2];
    a3 += (double)xv[3] * (double)wv[3];
  }
  lg[t][e] = (float)((a0 + a1) + (a2 + a3)) + rb[e];
  __syncthreads();
  if (tid < 16) {
    float v[16];
    #pragma unroll
    for (int i = 0; i < 16; ++i) { v[i] = lg[tid][i]; sc[tid][i] = 0.0f; }
    int idx[TOPK]; float val[TOPK];
    for (int k = 0; k < TOPK; ++k) {
      float best = -3.4e38f; int bi = 0;
      for (int i = 0; i < 16; ++i)
        if (v[i] > best) { best = v[i]; bi = i; }
      idx[k] = bi; val[k] = best; v[bi] = -3.4e38f;
    }
    float s = 0.0f, ev[TOPK];
    for (int k = 0; k < TOPK; ++k) { ev[k] = expf(val[k] - val[0]); s += ev[k]; }
    const int tok = t0 + tid;
    for (int k = 0; k < TOPK; ++k) {
      float wgt = ev[k] / s;
      sc[tid][idx[k]] = wgt;
      tk_idx[tok * TOPK + k] = idx[k];
      tk_w[tok * TOPK + k] = wgt;
    }
  }
  __syncthreads();
  scores[(size_t)(t0 + (tid >> 4)) * 16 + (tid & 15)] = sc[tid >> 4][tid & 15];
}

// ---------------- 2. deterministic group-by-expert (segmented parallel scan, pad 256) ----------------
__global__ __launch_bounds__(256)
void group_kernel(const int* __restrict__ tk_idx, const float* __restrict__ tk_w,
                  int* __restrict__ counts, int* __restrict__ offs,
                  int* __restrict__ tmap, float* __restrict__ wgrp) {
  __shared__ int hist[256][16];
  __shared__ int seg[16][16];
  __shared__ int cnt[16], eoff[16];
  const int tid = threadIdx.x;
  int loc[16];
  #pragma unroll
  for (int e = 0; e < 16; ++e) loc[e] = 0;
  const int base = tid * 32;
  int eid[32];
  for (int i = 0; i < 32; ++i) { int e = tk_idx[base + i]; eid[i] = e; loc[e]++; }
  #pragma unroll
  for (int e = 0; e < 16; ++e) hist[tid][e] = loc[e];
  __syncthreads();
  const int s = tid >> 4, e16 = tid & 15;
  {
    int sum = 0;
    #pragma unroll
    for (int j = 0; j < 16; ++j) sum += hist[s * 16 + j][e16];
    seg[s][e16] = sum;
  }
  __syncthreads();
  if (tid < 16) {
    int run = 0;
    #pragma unroll
    for (int s2 = 0; s2 < 16; ++s2) { int t = seg[s2][tid]; seg[s2][tid] = run; run += t; }
    cnt[tid] = run;
  }
  __syncthreads();
  {
    int run = seg[s][e16];
    #pragma unroll
    for (int j = 0; j < 16; ++j) { int t = hist[s * 16 + j][e16]; hist[s * 16 + j][e16] = run; run += t; }
  }
  __syncthreads();
  if (tid == 0) {
    int acc = 0;
    for (int e = 0; e < 16; ++e) { eoff[e] = acc; acc += (cnt[e] + BM - 1) / BM * BM; }
  }
  __syncthreads();
  if (tid < 16) { counts[tid] = cnt[tid]; offs[tid] = eoff[tid]; }
  int run[16];
  #pragma unroll
  for (int e = 0; e < 16; ++e) run[e] = hist[tid][e];
  for (int i = 0; i < 32; ++i) {
    int e = eid[i];
    int slot = eoff[e] + run[e]++;
    tmap[slot] = base + i;        // assignment id = t*4 + k
    wgrp[slot] = tk_w[base + i];
  }
}

// ---------------- 3. gather+convert x -> xg (group order, swizzled 256-row chunks) ----------------
__global__ __launch_bounds__(256)
void convert_x_kernel(const float* __restrict__ x, const int* __restrict__ tmap,
                      unsigned short* __restrict__ xg) {
  const int tile = blockIdx.x;     // 0..NTILE-1
  const int kt = blockIdx.y;       // 0..11
  const int r = threadIdx.x;       // 256 rows, 1 thread/row
  const int tok = tmap[tile * BM + r] >> 2;
  const float* src = x + (size_t)tok * H_DIM + kt * 64;
  unsigned short* dst = xg + ((size_t)tile * KT + kt) * CHUNK + r * BK;
  #pragma unroll
  for (int k8 = 0; k8 < 8; ++k8) {
    f32x4 a = *(const f32x4*)(src + 8 * k8);
    f32x4 b = *(const f32x4*)(src + 8 * k8 + 4);
    us8 o;
    #pragma unroll
    for (int j = 0; j < 4; ++j) { o[j] = f2bf(a[j]); o[4+j] = f2bf(b[j]); }
    *(us8*)&dst[8 * (k8 ^ (r & 7))] = o;
  }
}

// ---------------- 4. grouped GEMM1: x @ [gate|up](fp32, inline cvt) + GLU -> act ----------------
__global__ __launch_bounds__(256)
void gemm1_kernel(const unsigned short* __restrict__ xg, const float* __restrict__ gup,
                  const float* __restrict__ gupb,
                  const int* __restrict__ counts, const int* __restrict__ offs,
                  unsigned short* __restrict__ act) {
  // XCD-aware swizzle: 960 blocks = 8 x 120; bijective
  const int fb = blockIdx.x;
  const int swz = (fb & 7) * 120 + (fb >> 3);
  const int ft = swz % 12;
  const int ey = swz / 12;
  const int e = ey / MAXT1;
  const int tile = ey % MAXT1;
  const int count = counts[e];
  if (tile * BM >= count) return;
  const int tileg = (offs[e] >> 8) + tile;
  const int f0 = ft * 64;
  const int tid = threadIdx.x;
  const int wv = tid >> 6, lane = tid & 63;
  const int ml = lane & 15, lh = lane >> 4;

  __shared__ unsigned short lA[CHUNK];   // 32KB
  __shared__ unsigned short lBg[WTILE];  // 8KB
  __shared__ unsigned short lBu[WTILE];  // 8KB

  const unsigned short* ab = xg + (size_t)tileg * KT * CHUNK;
  const float* gup_e = gup + (size_t)e * H_DIM * TWOF;

  const int bn = tid & 63, kq = tid >> 6;

  f32x4 accg[4][4] = {};
  f32x4 accu[4][4] = {};

  for (int kt = 0; kt < KT; ++kt) {
    const unsigned short* as = ab + kt * CHUNK;
    #pragma unroll
    for (int i = 0; i < 8; ++i) gl_lds16(as + (i*256+tid)*8, &lA[(i*256+tid)*8]);
    #pragma unroll
    for (int half = 0; half < 2; ++half) {
      const int k8 = kq + half * 4;
      const float* gsrc = gup_e + (size_t)(kt * 64 + k8 * 8) * TWOF + 2 * (f0 + bn);
      uint4v g, u;
      #pragma unroll
      for (int j = 0; j < 4; ++j) {
        const float2 pa = *(const float2*)(gsrc + (size_t)(2 * j) * TWOF);
        const float2 pb = *(const float2*)(gsrc + (size_t)(2 * j + 1) * TWOF);
        g[j] = cvt_pk(pa.x, pb.x);
        u[j] = cvt_pk(pa.y, pb.y);
      }
      const int ad = bn * BK + 8 * (k8 ^ (bn & 7));
      *(uint4v*)&lBg[ad] = g;
      *(uint4v*)&lBu[ad] = u;
    }
    __syncthreads();
    #pragma unroll
    for (int ks = 0; ks < 2; ++ks) {
      const int slot = ks * 4 + lh;
      bf16x8 af[4];
      #pragma unroll
      for (int mf = 0; mf < 4; ++mf) {
        const int ar = wv * 64 + mf * 16 + ml;
        af[mf] = __builtin_bit_cast(bf16x8, *(const us8*)&lA[ar * BK + 8 * (slot ^ (ar & 7))]);
      }
      #pragma unroll
      for (int nf = 0; nf < 4; ++nf) {
        const int br = nf * 16 + ml;
        bf16x8 bg = __builtin_bit_cast(bf16x8, *(const us8*)&lBg[br * BK + 8 * (slot ^ (br & 7))]);
        bf16x8 bu = __builtin_bit_cast(bf16x8, *(const us8*)&lBu[br * BK + 8 * (slot ^ (br & 7))]);
        #pragma unroll
        for (int mf = 0; mf < 4; ++mf) {
          accg[mf][nf] = __builtin_amdgcn_mfma_f32_16x16x32_bf16(af[mf], bg, accg[mf][nf], 0, 0, 0);
          accu[mf][nf] = __builtin_amdgcn_mfma_f32_16x16x32_bf16(af[mf], bu, accu[mf][nf], 0, 0, 0);
        }
      }
    }
    __syncthreads();
  }
  // epilogue: activation, write swizzled chunk via LDS transit
  #pragma unroll
  for (int mf = 0; mf < 4; ++mf) {
    #pragma unroll
    for (int nf = 0; nf < 4; ++nf) {
      const int col = nf * 16 + ml;
      const int fc = f0 + col;
      const float bgv = gupb[(size_t)e * TWOF + 2 * fc];
      const float buv = gupb[(size_t)e * TWOF + 2 * fc + 1];
      #pragma unroll
      for (int r = 0; r < 4; ++r) {
        const int m = wv * 64 + mf * 16 + lh * 4 + r;
        float g = accg[mf][nf][r] + bgv;
        float u = accu[mf][nf][r] + buv;
        g = fminf(g, 7.0f);
        u = fminf(fmaxf(u, -7.0f), 7.0f);
        const float glu = g / (1.0f + expf(-1.702f * g));
        lA[m * BK + 8 * ((col >> 3) ^ (m & 7)) + (col & 7)] = f2bf((u + 1.0f) * glu);
      }
    }
  }
  __syncthreads();
  unsigned short* ob = act + ((size_t)tileg * KT + ft) * CHUNK;
  #pragma unroll
  for (int i = 0; i < 8; ++i)
    *(us8*)&ob[(i*256+tid)*8] = *(const us8*)&lA[(i*256+tid)*8];
}

// ---------------- 5. grouped GEMM2: act @ down(fp32, inline cvt) + bias, x route weight ----------------
__global__ __launch_bounds__(256)
void gemm2_kernel(const unsigned short* __restrict__ act, const float* __restrict__ dwn,
                  const float* __restrict__ dwnb, const int* __restrict__ counts,
                  const int* __restrict__ offs, const int* __restrict__ tmap,
                  const float* __restrict__ wgrp, float* __restrict__ partial) {
  // XCD-aware swizzle: 960 blocks = 8 x 120; bijective (R10 bug: used *60)
  const int fb = blockIdx.x;
  const int swz = (fb & 7) * 120 + (fb >> 3);
  const int ft = swz % 12;
  const int ey = swz / 12;
  const int e = ey / MAXT1;
  const int tile = ey % MAXT1;
  const int count = counts[e];
  if (tile * BM >= count) return;
  const int off = offs[e];
  const int tileg = (off >> 8) + tile;
  const int h0 = ft * 64;
  const int tid = threadIdx.x;
  const int wv = tid >> 6, lane = tid & 63;
  const int ml = lane & 15, lh = lane >> 4;

  __shared__ unsigned short lA[CHUNK];   // 32KB
  __shared__ unsigned short lB[WTILE];   // 8KB

  const unsigned short* ab = act + (size_t)tileg * KT * CHUNK;
  const float* dwn_e = dwn + (size_t)e * F_DIM * H_DIM;

  const int bn = tid & 63, kq = tid >> 6;

  f32x4 acc[4][4] = {};

  for (int kt = 0; kt < KT; ++kt) {
    const unsigned short* as = ab + kt * CHUNK;
    #pragma unroll
    for (int i = 0; i < 8; ++i) gl_lds16(as + (i*256+tid)*8, &lA[(i*256+tid)*8]);
    #pragma unroll
    for (int half = 0; half < 2; ++half) {
      const int k8 = kq + half * 4;
      const float* dsrc = dwn_e + (size_t)(kt * 64 + k8 * 8) * H_DIM + h0 + bn;
      uint4v dv;
      #pragma unroll
      for (int j = 0; j < 4; ++j) {
        const float a = dsrc[(size_t)(2 * j) * H_DIM];
        const float b = dsrc[(size_t)(2 * j + 1) * H_DIM];
        dv[j] = cvt_pk(a, b);
      }
      *(uint4v*)&lB[bn * BK + 8 * (k8 ^ (bn & 7))] = dv;
    }
    __syncthreads();
    #pragma unroll
    for (int ks = 0; ks < 2; ++ks) {
      const int slot = ks * 4 + lh;
      bf16x8 af[4];
      #pragma unroll
      for (int mf = 0; mf < 4; ++mf) {
        const int ar = wv * 64 + mf * 16 + ml;
        af[mf] = __builtin_bit_cast(bf16x8, *(const us8*)&lA[ar * BK + 8 * (slot ^ (ar & 7))]);
      }
      #pragma unroll
      for (int nf = 0; nf < 4; ++nf) {
        const int br = nf * 16 + ml;
        bf16x8 bv = __builtin_bit_cast(bf16x8, *(const us8*)&lB[br * BK + 8 * (slot ^ (br & 7))]);
        #pragma unroll
        for (int mf = 0; mf < 4; ++mf)
          acc[mf][nf] = __builtin_amdgcn_mfma_f32_16x16x32_bf16(af[mf], bv, acc[mf][nf], 0, 0, 0);
      }
    }
    __syncthreads();
  }
  #pragma unroll
  for (int mf = 0; mf < 4; ++mf) {
    #pragma unroll
    for (int nf = 0; nf < 4; ++nf) {
      const int hc = h0 + nf * 16 + ml;
      const float bias = dwnb[(size_t)e * H_DIM + hc];
      #pragma unroll
      for (int r = 0; r < 4; ++r) {
        const int m = tile * BM + wv * 64 + mf * 16 + lh * 4 + r;
        if (m < count) {
          const int slot = off + m;
          partial[(size_t)tmap[slot] * H_DIM + hc] = wgrp[slot] * (acc[mf][nf][r] + bias);
        }
      }
    }
  }
}

// ---------------- 6. reduce partials over k ----------------
__global__ __launch_bounds__(256)
void reduce_kernel(const float* __restrict__ partial, float* __restrict__ out) {
  const int idx = blockIdx.x * 256 + threadIdx.x;
  const int v = idx * 4;
  const int t = v / H_DIM;
  const int h = v - t * H_DIM;
  f32x4 s = {0, 0, 0, 0};
  #pragma unroll
  for (int k = 0; k < 4; ++k) {
    const f32x4 p = *(const f32x4*)&partial[(size_t)(t * 4 + k) * H_DIM + h];
    s += p;
  }
  *(f32x4*)&out[v] = s;
}

extern "C" void kernel_launch(void* const* d_in, const int* in_sizes, int n_in,
                              void* d_out, int out_size, void* d_ws, size_t ws_size,
                              hipStream_t stream) {
  const float* x    = (const float*)d_in[0];
  const float* rw   = (const float*)d_in[1];
  const float* rb   = (const float*)d_in[2];
  const float* gup  = (const float*)d_in[3];
  const float* gupb = (const float*)d_in[4];
  const float* dwn  = (const float*)d_in[5];
  const float* dwnb = (const float*)d_in[6];
  float* out = (float*)d_out;
  float* scores = out + (size_t)T_TOK * H_DIM;

  char* w = (char*)d_ws;
  int*   tk_idx = (int*)w;            w += NASSIGN * 4;
  float* tk_w   = (float*)w;          w += NASSIGN * 4;
  int*   counts = (int*)w;            w += 64;
  int*   offs   = (int*)w;            w += 64;
  int*   tmap   = (int*)w;            w += NSLOTP * 4;
  float* wgrp   = (float*)w;          w += NSLOTP * 4;
  unsigned short* xg = (unsigned short*)w;  w += (size_t)NTILE * KT * CHUNK * 2;
  unsigned short* act = (unsigned short*)w; w += (size_t)NTILE * KT * CHUNK * 2;
  float* partial = (float*)w;         w += (size_t)NASSIGN * H_DIM * 4;

  router_kernel<<<T_TOK / 16, 256, 0, stream>>>(x, rw, rb, scores, tk_idx, tk_w, tmap, wgrp);
  group_kernel<<<1, 256, 0, stream>>>(tk_idx, tk_w, counts, offs, tmap, wgrp);
  convert_x_kernel<<<dim3(NTILE, KT), 256, 0, stream>>>(x, tmap, xg);
  gemm1_kernel<<<12 * E_NUM * MAXT1, 256, 0, stream>>>(
      xg, gup, gupb, counts, offs, act);
  gemm2_kernel<<<12 * E_NUM * MAXT1, 256, 0, stream>>>(
      act, dwn, dwnb, counts, offs, tmap, wgrp, partial);
  reduce_kernel<<<(T_TOK * H_DIM / 4) / 256, 256, 0, stream>>>(partial, out);
}

// Round 12
// 153.222 us; speedup vs baseline: 1.1771x; 1.1771x over previous
//
#include <hip/hip_runtime.h>
#include <hip/hip_bf16.h>

#define T_TOK 2048
#define H_DIM 768
#define E_NUM 16
#define F_DIM 768
#define TWOF 1536
#define TOPK 4
#define NASSIGN 8192
#define BM 128
#define BK 64
#define BN 64
#define KT 12            /* 768/64 k-tiles */
#define NTILE 80         /* padded slots / BM = 10240/128 */
#define NSLOTP (NTILE * BM)
#define MAXT1 10         /* max tiles per expert (count <= 1280) */
#define CHUNK (BM * BK)  /* 8192 halfwords per A/act chunk */
#define WTILE (BN * BK)  /* 4096 halfwords per weight tile */
#define NCVT 4608        /* convert_w blocks: 32 x 12 x 12 */
#define NRTR 256         /* router blocks: 2048 / 8 */

typedef __bf16 bf16x8 __attribute__((ext_vector_type(8)));
typedef unsigned short us8 __attribute__((ext_vector_type(8)));
typedef float f32x4 __attribute__((ext_vector_type(4)));

__device__ __forceinline__ unsigned short f2bf(float f) {
  unsigned u = __float_as_uint(f);
  u += 0x7FFF + ((u >> 16) & 1);
  return (unsigned short)(u >> 16);
}

__device__ __forceinline__ void gl_lds16(const unsigned short* g, unsigned short* l) {
  __builtin_amdgcn_global_load_lds(
      (const __attribute__((address_space(1))) unsigned int*)g,
      (__attribute__((address_space(3))) unsigned int*)l, 16, 0, 0);
}

// ---------------- 1. prep: router (blocks 0..255) + weight convert (blocks 256..4863) ----------------
__global__ __launch_bounds__(256)
void prep_kernel(const float* __restrict__ gup, const float* __restrict__ dwn,
                 unsigned short* __restrict__ gw, unsigned short* __restrict__ uw,
                 unsigned short* __restrict__ dw,
                 const float* __restrict__ x, const float* __restrict__ rw,
                 const float* __restrict__ rb, float* __restrict__ scores,
                 int* __restrict__ tk_idx, float* __restrict__ tk_w,
                 int* __restrict__ tmap, float* __restrict__ wgrp) {
  __shared__ unsigned short tg[WTILE], tu[WTILE];   // 16 KB (convert part)
  __shared__ float lg[8][16], sc[8][16];            // 1 KB  (router part)
  const int bid = blockIdx.x;
  const int tid = threadIdx.x;
  if (bid < NRTR) {
    // ---- router: 8 tokens/block, 32 lanes/token, LDS-free dot ----
    const int t0 = bid * 8;
    if (tid < 40) {  // 256 blocks x 40 = NSLOTP padded-slot init
      tmap[bid * 40 + tid] = 0;
      wgrp[bid * 40 + tid] = 0.0f;
    }
    const int lane32 = tid & 31, tok = tid >> 5;
    const int e = lane32 & 15, q2 = lane32 >> 4;
    const int t = t0 + tok;
    const float* xr = x + (size_t)t * H_DIM + q2 * 384;
    const float* wr = rw + (size_t)e * H_DIM + q2 * 384;
    double a0 = 0, a1 = 0, a2 = 0, a3 = 0;
    #pragma unroll 4
    for (int h = 0; h < 384; h += 4) {
      const f32x4 xv = *(const f32x4*)(xr + h);
      const f32x4 wv = *(const f32x4*)(wr + h);
      a0 += (double)xv[0] * (double)wv[0];
      a1 += (double)xv[1] * (double)wv[1];
      a2 += (double)xv[2] * (double)wv[2];
      a3 += (double)xv[3] * (double)wv[3];
    }
    double acc = (a0 + a1) + (a2 + a3);
    acc += __shfl_xor(acc, 16, 64);   // combine the two h-halves (lanes within same 32-group)
    if (q2 == 0) lg[tok][e] = (float)acc + rb[e];
    __syncthreads();
    if (lane32 == 0) {
      float v[16];
      #pragma unroll
      for (int i = 0; i < 16; ++i) { v[i] = lg[tok][i]; sc[tok][i] = 0.0f; }
      int idx[TOPK]; float val[TOPK];
      for (int k = 0; k < TOPK; ++k) {
        float best = -3.4e38f; int bi = 0;
        for (int i = 0; i < 16; ++i)
          if (v[i] > best) { best = v[i]; bi = i; }
        idx[k] = bi; val[k] = best; v[bi] = -3.4e38f;
      }
      float s = 0.0f, ev[TOPK];
      for (int k = 0; k < TOPK; ++k) { ev[k] = expf(val[k] - val[0]); s += ev[k]; }
      for (int k = 0; k < TOPK; ++k) {
        float wgt = ev[k] / s;
        sc[tok][idx[k]] = wgt;
        tk_idx[t * TOPK + k] = idx[k];
        tk_w[t * TOPK + k] = wgt;
      }
    }
    __syncthreads();
    if (tid < 128)
      scores[(size_t)(t0 + (tid >> 4)) * 16 + (tid & 15)] = sc[tid >> 4][tid & 15];
  } else {
    // ---- weight convert (R4-proven pattern, 256-thread variant) ----
    const int cbid = bid - NRTR;
    const int z = cbid / 144, rem = cbid % 144;
    const int kt = rem / 12, ft = rem % 12;
    const int n = tid & 63, kq = tid >> 6;
    if (z < 16) {
      const int e = z;
      #pragma unroll
      for (int half = 0; half < 2; ++half) {
        const int k8 = kq + half * 4;
        const float* src = gup + ((size_t)(e * H_DIM + kt * 64 + k8 * 8)) * TWOF
                               + 2 * (ft * 64 + n);
        us8 g, u;
        #pragma unroll
        for (int j = 0; j < 8; ++j) {
          const float2 p = *(const float2*)(src + (size_t)j * TWOF);
          g[j] = f2bf(p.x); u[j] = f2bf(p.y);
        }
        const int doff = n * BK + 8 * (k8 ^ (n & 7));
        *(us8*)&tg[doff] = g;
        *(us8*)&tu[doff] = u;
      }
      __syncthreads();
      const size_t tb = (((size_t)e * KT + kt) * 12 + ft) * WTILE;
      #pragma unroll
      for (int p = 0; p < 2; ++p) {
        *(us8*)&gw[tb + (p * 256 + tid) * 8] = *(const us8*)&tg[(p * 256 + tid) * 8];
        *(us8*)&uw[tb + (p * 256 + tid) * 8] = *(const us8*)&tu[(p * 256 + tid) * 8];
      }
    } else {
      const int e = z - 16;
      #pragma unroll
      for (int half = 0; half < 2; ++half) {
        const int k8 = kq + half * 4;
        const float* src = dwn + ((size_t)(e * F_DIM + kt * 64 + k8 * 8)) * H_DIM
                               + ft * 64 + n;
        us8 o;
        #pragma unroll
        for (int j = 0; j < 8; ++j) o[j] = f2bf(src[(size_t)j * H_DIM]);
        *(us8*)&tg[n * BK + 8 * (k8 ^ (n & 7))] = o;
      }
      __syncthreads();
      const size_t tb = (((size_t)e * KT + kt) * 12 + ft) * WTILE;
      #pragma unroll
      for (int p = 0; p < 2; ++p)
        *(us8*)&dw[tb + (p * 256 + tid) * 8] = *(const us8*)&tg[(p * 256 + tid) * 8];
    }
  }
}

// ---------------- 2. deterministic group-by-expert (segmented parallel scan) ----------------
__global__ __launch_bounds__(256)
void group_kernel(const int* __restrict__ tk_idx, const float* __restrict__ tk_w,
                  int* __restrict__ counts, int* __restrict__ offs,
                  int* __restrict__ tmap, float* __restrict__ wgrp) {
  __shared__ int hist[256][16];
  __shared__ int seg[16][16];
  __shared__ int cnt[16], eoff[16];
  const int tid = threadIdx.x;
  int loc[16];
  #pragma unroll
  for (int e = 0; e < 16; ++e) loc[e] = 0;
  const int base = tid * 32;
  int eid[32];
  for (int i = 0; i < 32; ++i) { int e = tk_idx[base + i]; eid[i] = e; loc[e]++; }
  #pragma unroll
  for (int e = 0; e < 16; ++e) hist[tid][e] = loc[e];
  __syncthreads();
  const int s = tid >> 4, e16 = tid & 15;
  {
    int sum = 0;
    #pragma unroll
    for (int j = 0; j < 16; ++j) sum += hist[s * 16 + j][e16];
    seg[s][e16] = sum;
  }
  __syncthreads();
  if (tid < 16) {
    int run = 0;
    #pragma unroll
    for (int s2 = 0; s2 < 16; ++s2) { int t = seg[s2][tid]; seg[s2][tid] = run; run += t; }
    cnt[tid] = run;
  }
  __syncthreads();
  {
    int run = seg[s][e16];
    #pragma unroll
    for (int j = 0; j < 16; ++j) { int t = hist[s * 16 + j][e16]; hist[s * 16 + j][e16] = run; run += t; }
  }
  __syncthreads();
  if (tid == 0) {
    int acc = 0;
    for (int e = 0; e < 16; ++e) { eoff[e] = acc; acc += (cnt[e] + BM - 1) / BM * BM; }
  }
  __syncthreads();
  if (tid < 16) { counts[tid] = cnt[tid]; offs[tid] = eoff[tid]; }
  int run[16];
  #pragma unroll
  for (int e = 0; e < 16; ++e) run[e] = hist[tid][e];
  for (int i = 0; i < 32; ++i) {
    int e = eid[i];
    int slot = eoff[e] + run[e]++;
    tmap[slot] = base + i;        // assignment id = t*4 + k
    wgrp[slot] = tk_w[base + i];
  }
}

// ---------------- 3. gather+convert x -> xg (group order, swizzled chunks) ----------------
__global__ __launch_bounds__(256)
void convert_x_kernel(const float* __restrict__ x, const int* __restrict__ tmap,
                      unsigned short* __restrict__ xg) {
  const int tile = blockIdx.x;     // 0..NTILE-1
  const int kt = blockIdx.y;       // 0..11
  const int tid = threadIdx.x;
  const int r = tid >> 1;          // 128 rows, 2 threads/row
  const int c0 = (tid & 1) * 32;
  const int tok = tmap[tile * BM + r] >> 2;
  const float* src = x + (size_t)tok * H_DIM + kt * 64 + c0;
  unsigned short* dst = xg + ((size_t)tile * KT + kt) * CHUNK + r * BK;
  #pragma unroll
  for (int qq = 0; qq < 4; ++qq) {
    f32x4 a = *(const f32x4*)(src + 8 * qq);
    f32x4 b = *(const f32x4*)(src + 8 * qq + 4);
    us8 o;
    #pragma unroll
    for (int j = 0; j < 4; ++j) { o[j] = f2bf(a[j]); o[4+j] = f2bf(b[j]); }
    const int k8 = (c0 >> 3) + qq;
    *(us8*)&dst[8 * (k8 ^ (r & 7))] = o;
  }
}

// ---------------- 4. grouped GEMM1: xg @ [gate|up] + GLU -> act (single-buffer) ----------------
__global__ __launch_bounds__(256)
void gemm1_kernel(const unsigned short* __restrict__ xg, const unsigned short* __restrict__ gw,
                  const unsigned short* __restrict__ uw, const float* __restrict__ gupb,
                  const int* __restrict__ counts, const int* __restrict__ offs,
                  unsigned short* __restrict__ act) {
  const int e = blockIdx.y / MAXT1;
  const int tile = blockIdx.y % MAXT1;
  const int count = counts[e];
  if (tile * BM >= count) return;
  const int tileg = (offs[e] >> 7) + tile;
  const int ft = blockIdx.x;
  const int tid = threadIdx.x;
  const int wv = tid >> 6, lane = tid & 63;
  const int ml = lane & 15, lh = lane >> 4;

  __shared__ unsigned short lA[CHUNK];   // 16KB
  __shared__ unsigned short lBg[WTILE];  // 8KB
  __shared__ unsigned short lBu[WTILE];  // 8KB

  const unsigned short* ab = xg + (size_t)tileg * KT * CHUNK;
  const unsigned short* gb = gw + ((size_t)e * KT * 12 + ft) * WTILE;
  const unsigned short* ub = uw + ((size_t)e * KT * 12 + ft) * WTILE;

  f32x4 accg[2][4] = {};
  f32x4 accu[2][4] = {};

  for (int kt = 0; kt < KT; ++kt) {
    const unsigned short* as = ab + kt * CHUNK;
    const unsigned short* gs = gb + (size_t)kt * 12 * WTILE;
    const unsigned short* us = ub + (size_t)kt * 12 * WTILE;
    #pragma unroll
    for (int i = 0; i < 4; ++i) gl_lds16(as + (i*256+tid)*8, &lA[(i*256+tid)*8]);
    #pragma unroll
    for (int i = 0; i < 2; ++i) gl_lds16(gs + (i*256+tid)*8, &lBg[(i*256+tid)*8]);
    #pragma unroll
    for (int i = 0; i < 2; ++i) gl_lds16(us + (i*256+tid)*8, &lBu[(i*256+tid)*8]);
    __syncthreads();
    #pragma unroll
    for (int ks = 0; ks < 2; ++ks) {
      const int slot = ks * 4 + lh;
      bf16x8 af0, af1;
      {
        const int ar0 = wv * 32 + ml;
        const int ar1 = wv * 32 + 16 + ml;
        af0 = __builtin_bit_cast(bf16x8, *(const us8*)&lA[ar0 * BK + 8 * (slot ^ (ar0 & 7))]);
        af1 = __builtin_bit_cast(bf16x8, *(const us8*)&lA[ar1 * BK + 8 * (slot ^ (ar1 & 7))]);
      }
      #pragma unroll
      for (int nf = 0; nf < 4; ++nf) {
        const int br = nf * 16 + ml;
        bf16x8 bg = __builtin_bit_cast(bf16x8, *(const us8*)&lBg[br * BK + 8 * (slot ^ (br & 7))]);
        bf16x8 bu = __builtin_bit_cast(bf16x8, *(const us8*)&lBu[br * BK + 8 * (slot ^ (br & 7))]);
        accg[0][nf] = __builtin_amdgcn_mfma_f32_16x16x32_bf16(af0, bg, accg[0][nf], 0, 0, 0);
        accg[1][nf] = __builtin_amdgcn_mfma_f32_16x16x32_bf16(af1, bg, accg[1][nf], 0, 0, 0);
        accu[0][nf] = __builtin_amdgcn_mfma_f32_16x16x32_bf16(af0, bu, accu[0][nf], 0, 0, 0);
        accu[1][nf] = __builtin_amdgcn_mfma_f32_16x16x32_bf16(af1, bu, accu[1][nf], 0, 0, 0);
      }
    }
    __syncthreads();
  }
  // epilogue: activation, write swizzled chunk via LDS transit
  #pragma unroll
  for (int mf = 0; mf < 2; ++mf) {
    #pragma unroll
    for (int nf = 0; nf < 4; ++nf) {
      const int col = nf * 16 + ml;
      const int fc = ft * 64 + col;
      const float bgv = gupb[(size_t)e * TWOF + 2 * fc];
      const float buv = gupb[(size_t)e * TWOF + 2 * fc + 1];
      #pragma unroll
      for (int r = 0; r < 4; ++r) {
        const int m = wv * 32 + mf * 16 + lh * 4 + r;
        float g = accg[mf][nf][r] + bgv;
        float u = accu[mf][nf][r] + buv;
        g = fminf(g, 7.0f);
        u = fminf(fmaxf(u, -7.0f), 7.0f);
        const float glu = g / (1.0f + expf(-1.702f * g));
        lA[m * BK + 8 * ((col >> 3) ^ (m & 7)) + (col & 7)] = f2bf((u + 1.0f) * glu);
      }
    }
  }
  __syncthreads();
  unsigned short* ob = act + ((size_t)tileg * KT + ft) * CHUNK;
  #pragma unroll
  for (int i = 0; i < 4; ++i)
    *(us8*)&ob[(i*256+tid)*8] = *(const us8*)&lA[(i*256+tid)*8];
}

// ---------------- 5. grouped GEMM2: act @ down + bias, x route weight -> partial ----------------
__global__ __launch_bounds__(256)
void gemm2_kernel(const unsigned short* __restrict__ act, const unsigned short* __restrict__ dw,
                  const float* __restrict__ dwnb, const int* __restrict__ counts,
                  const int* __restrict__ offs, const int* __restrict__ tmap,
                  const float* __restrict__ wgrp, float* __restrict__ partial) {
  const int e = blockIdx.y / MAXT1;
  const int tile = blockIdx.y % MAXT1;
  const int count = counts[e];
  if (tile * BM >= count) return;
  const int off = offs[e];
  const int tileg = (off >> 7) + tile;
  const int ft = blockIdx.x;  // h-tile
  const int tid = threadIdx.x;
  const int wv = tid >> 6, lane = tid & 63;
  const int ml = lane & 15, lh = lane >> 4;

  __shared__ unsigned short lA[CHUNK];
  __shared__ unsigned short lB[WTILE];

  const unsigned short* ab = act + (size_t)tileg * KT * CHUNK;
  const unsigned short* bb = dw + ((size_t)e * KT * 12 + ft) * WTILE;

  f32x4 acc[2][4] = {};

  for (int kt = 0; kt < KT; ++kt) {
    const unsigned short* as = ab + kt * CHUNK;
    const unsigned short* bs = bb + (size_t)kt * 12 * WTILE;
    #pragma unroll
    for (int i = 0; i < 4; ++i) gl_lds16(as + (i*256+tid)*8, &lA[(i*256+tid)*8]);
    #pragma unroll
    for (int i = 0; i < 2; ++i) gl_lds16(bs + (i*256+tid)*8, &lB[(i*256+tid)*8]);
    __syncthreads();
    #pragma unroll
    for (int ks = 0; ks < 2; ++ks) {
      const int slot = ks * 4 + lh;
      bf16x8 af0, af1;
      {
        const int ar0 = wv * 32 + ml;
        const int ar1 = wv * 32 + 16 + ml;
        af0 = __builtin_bit_cast(bf16x8, *(const us8*)&lA[ar0 * BK + 8 * (slot ^ (ar0 & 7))]);
        af1 = __builtin_bit_cast(bf16x8, *(const us8*)&lA[ar1 * BK + 8 * (slot ^ (ar1 & 7))]);
      }
      #pragma unroll
      for (int nf = 0; nf < 4; ++nf) {
        const int br = nf * 16 + ml;
        bf16x8 bv = __builtin_bit_cast(bf16x8, *(const us8*)&lB[br * BK + 8 * (slot ^ (br & 7))]);
        acc[0][nf] = __builtin_amdgcn_mfma_f32_16x16x32_bf16(af0, bv, acc[0][nf], 0, 0, 0);
        acc[1][nf] = __builtin_amdgcn_mfma_f32_16x16x32_bf16(af1, bv, acc[1][nf], 0, 0, 0);
      }
    }
    __syncthreads();
  }
  #pragma unroll
  for (int mf = 0; mf < 2; ++mf) {
    #pragma unroll
    for (int nf = 0; nf < 4; ++nf) {
      const int hc = ft * 64 + nf * 16 + ml;
      const float bias = dwnb[(size_t)e * H_DIM + hc];
      #pragma unroll
      for (int r = 0; r < 4; ++r) {
        const int m = tile * BM + wv * 32 + mf * 16 + lh * 4 + r;
        if (m < count) {
          const int slot = off + m;
          partial[(size_t)tmap[slot] * H_DIM + hc] = wgrp[slot] * (acc[mf][nf][r] + bias);
        }
      }
    }
  }
}

// ---------------- 6. reduce partials over k ----------------
__global__ __launch_bounds__(256)
void reduce_kernel(const float* __restrict__ partial, float* __restrict__ out) {
  const int idx = blockIdx.x * 256 + threadIdx.x;
  const int v = idx * 4;
  const int t = v / H_DIM;
  const int h = v - t * H_DIM;
  f32x4 s = {0, 0, 0, 0};
  #pragma unroll
  for (int k = 0; k < 4; ++k) {
    const f32x4 p = *(const f32x4*)&partial[(size_t)(t * 4 + k) * H_DIM + h];
    s += p;
  }
  *(f32x4*)&out[v] = s;
}

extern "C" void kernel_launch(void* const* d_in, const int* in_sizes, int n_in,
                              void* d_out, int out_size, void* d_ws, size_t ws_size,
                              hipStream_t stream) {
  const float* x    = (const float*)d_in[0];
  const float* rw   = (const float*)d_in[1];
  const float* rb   = (const float*)d_in[2];
  const float* gup  = (const float*)d_in[3];
  const float* gupb = (const float*)d_in[4];
  const float* dwn  = (const float*)d_in[5];
  const float* dwnb = (const float*)d_in[6];
  float* out = (float*)d_out;
  float* scores = out + (size_t)T_TOK * H_DIM;

  char* w = (char*)d_ws;
  int*   tk_idx = (int*)w;            w += NASSIGN * 4;
  float* tk_w   = (float*)w;          w += NASSIGN * 4;
  int*   counts = (int*)w;            w += 64;
  int*   offs   = (int*)w;            w += 64;
  int*   tmap   = (int*)w;            w += NSLOTP * 4;
  float* wgrp   = (float*)w;          w += NSLOTP * 4;
  unsigned short* gw = (unsigned short*)w; w += (size_t)E_NUM * KT * 12 * WTILE * 2;
  unsigned short* uw = (unsigned short*)w; w += (size_t)E_NUM * KT * 12 * WTILE * 2;
  unsigned short* dw = (unsigned short*)w; w += (size_t)E_NUM * KT * 12 * WTILE * 2;
  unsigned short* xg = (unsigned short*)w; w += (size_t)NTILE * KT * CHUNK * 2;
  unsigned short* act = (unsigned short*)w; w += (size_t)NTILE * KT * CHUNK * 2;
  float* partial = (float*)w;         w += (size_t)NASSIGN * H_DIM * 4;

  prep_kernel<<<NCVT + NRTR, 256, 0, stream>>>(
      gup, dwn, gw, uw, dw, x, rw, rb, scores, tk_idx, tk_w, tmap, wgrp);
  group_kernel<<<1, 256, 0, stream>>>(tk_idx, tk_w, counts, offs, tmap, wgrp);
  convert_x_kernel<<<dim3(NTILE, KT), 256, 0, stream>>>(x, tmap, xg);
  gemm1_kernel<<<dim3(12, E_NUM * MAXT1), 256, 0, stream>>>(
      xg, gw, uw, gupb, counts, offs, act);
  gemm2_kernel<<<dim3(12, E_NUM * MAXT1), 256, 0, stream>>>(
      act, dw, dwnb, counts, offs, tmap, wgrp, partial);
  reduce_kernel<<<(T_TOK * H_DIM / 4) / 256, 256, 0, stream>>>(partial, out);
}